// Round 7
// baseline (210.609 us; speedup 1.0000x reference)
//
#include <hip/hip_runtime.h>

#define BB 16
#define CC 256
#define NN 1024

typedef _Float16 f16;
typedef __attribute__((ext_vector_type(8))) _Float16 half8;   // MFMA A/B frag (4 VGPRs)
typedef __attribute__((ext_vector_type(4))) float f32x4;      // MFMA C/D frag

__device__ __forceinline__ half8 ldg8(const f16* p) {
  return *reinterpret_cast<const half8*>(p);
}

// async global->LDS, 16B per lane; lds base must be wave-uniform (HW adds lane*16)
__device__ __forceinline__ void gll16(const f16* g, f16* l) {
  __builtin_amdgcn_global_load_lds((const __attribute__((address_space(1))) void*)g,
                                   (__attribute__((address_space(3))) void*)l, 16, 0, 0);
}

#define VMCNT(n) asm volatile("s_waitcnt vmcnt(" #n ")" ::: "memory")
#define BAR() __builtin_amdgcn_s_barrier()

// stage one contiguous 64 KB chunk (32768 f16) with 1024 threads (16 waves): 4 issues/thread.
__device__ __forceinline__ void stage64k16(const f16* __restrict__ g, f16* l, int wave, int lane) {
#pragma unroll
  for (int k = 0; k < 4; ++k) {
    int ob = k * 8192 + wave * 512;      // 16 waves x 512 = 8192 per k
    gll16(g + ob + lane * 8, l + ob);
  }
}

// ---------------- weight pack: W fp32 [ci][co] -> frag-packed f16 wp[(ct*8+kc)*512 + lane*8] ----
struct WP5 {
  const float* s[5];
  f16* d[5];
};

__global__ void __launch_bounds__(256) k_packW(WP5 p) {
  __shared__ float ws[256][17];
  int m = blockIdx.y, ct = blockIdx.x;
  const float* W = p.s[m];
  f16* wp = p.d[m];
  int tid = threadIdx.x;
  int col = tid & 15, cig = tid >> 4;
#pragma unroll
  for (int pg = 0; pg < 16; ++pg) {
    int ci = pg * 16 + cig;
    ws[ci][col] = W[(size_t)ci * 256 + ct * 16 + col];
  }
  __syncthreads();
  int lane = tid & 63, wave = tid >> 6;
  int row16 = lane & 15, quad = lane >> 4;
#pragma unroll
  for (int kk = 0; kk < 2; ++kk) {
    int kc = wave * 2 + kk;
    half8 o;
#pragma unroll
    for (int j = 0; j < 8; ++j) o[j] = (f16)ws[kc * 32 + quad * 8 + j][row16];
    *reinterpret_cast<half8*>(wp + ((size_t)ct * 8 + kc) * 512 + lane * 8) = o;
  }
}

// ---------------- QKV (z-merged, unchanged from R3/R4) ----------------
struct QkvSmem {
  union {
    struct { f16 hi[32][264]; f16 lo[32][264]; } ts;
    f16 ex[2][16][264];
    f16 exv[256][40];
  };
};

__global__ void __launch_bounds__(256) k_qkv(const float* __restrict__ x,
    const f16* __restrict__ wqp, const f16* __restrict__ wkp, const f16* __restrict__ wvp,
    const float* __restrict__ bq, const float* __restrict__ bk, const float* __restrict__ bv,
    f16* __restrict__ qp, f16* __restrict__ kp, f16* __restrict__ vp, int b_base) {
  __shared__ QkvSmem sm;
  int bl = blockIdx.x, bg = b_base + bl, n0 = blockIdx.y * 32;
  int tid = threadIdx.x, wave = tid >> 6, lane = tid & 63;
  int row16 = lane & 15, quad = lane >> 4;
  int g = wave >> 1, h = wave & 1;

#pragma unroll
  for (int e = tid; e < 2048; e += 256) {
    int c = e >> 3, n4 = (e & 7) << 2;
    float4 u = *reinterpret_cast<const float4*>(x + (size_t)(bg * CC + c) * NN + n0 + n4);
    float uv[4] = {u.x, u.y, u.z, u.w};
#pragma unroll
    for (int i = 0; i < 4; ++i) {
      f16 hh = (f16)uv[i];
      sm.ts.hi[n4 + i][c] = hh;
      sm.ts.lo[n4 + i][c] = (f16)(uv[i] - (float)hh);
    }
  }
  __syncthreads();

  half8 ah[8], al[8];
#pragma unroll
  for (int kc = 0; kc < 8; ++kc) {
    ah[kc] = *reinterpret_cast<const half8*>(&sm.ts.hi[g * 16 + row16][kc * 32 + quad * 8]);
    al[kc] = *reinterpret_cast<const half8*>(&sm.ts.lo[g * 16 + row16][kc * 32 + quad * 8]);
  }
  __syncthreads();

  const f16* WTs[2]    = {wqp, wkp};
  const float* biases[2] = {bq, bk};
  f16* outs[2]         = {qp, kp};
#pragma unroll
  for (int z = 0; z < 2; ++z) {
    const f16* WT = WTs[z];
    const float* bias = biases[z];
    f16* outp = outs[z];
#pragma unroll
    for (int cp = 0; cp < 2; ++cp) {
      f32x4 acch[4], accl[4];
#pragma unroll
      for (int u = 0; u < 4; ++u) { acch[u] = {0.f,0.f,0.f,0.f}; accl[u] = {0.f,0.f,0.f,0.f}; }
#pragma unroll
      for (int kc = 0; kc < 8; ++kc) {
#pragma unroll
        for (int u = 0; u < 4; ++u) {
          int ct = h * 8 + cp * 4 + u;
          half8 b = ldg8(WT + ((size_t)ct * 8 + kc) * 512 + lane * 8);
          acch[u] = __builtin_amdgcn_mfma_f32_16x16x32_f16(ah[kc], b, acch[u], 0, 0, 0);
          accl[u] = __builtin_amdgcn_mfma_f32_16x16x32_f16(al[kc], b, accl[u], 0, 0, 0);
        }
      }
#pragma unroll
      for (int u = 0; u < 4; ++u) {
        int ct = h * 8 + cp * 4 + u;
        int co = ct * 16 + row16;
        float bb = bias[co];
#pragma unroll
        for (int r = 0; r < 4; ++r)
          sm.ex[g][quad * 4 + r][co] = (f16)(acch[u][r] + accl[u][r] + bb);
      }
    }
    const f16* exr = &sm.ex[g][row16][0];
    size_t fb = ((size_t)bl * 64 + (n0 >> 4) + g) * 8;
#pragma unroll
    for (int k = 0; k < 4; ++k) {
      int kc = h * 4 + k;
      half8 hv = *reinterpret_cast<const half8*>(exr + kc * 32 + quad * 8);
      *reinterpret_cast<half8*>(outp + (fb + kc) * 512 + lane * 8) = hv;
    }
  }
  __syncthreads();

#pragma unroll
  for (int cp = 0; cp < 2; ++cp) {
    f32x4 acch[4], accl[4];
#pragma unroll
    for (int u = 0; u < 4; ++u) { acch[u] = {0.f,0.f,0.f,0.f}; accl[u] = {0.f,0.f,0.f,0.f}; }
#pragma unroll
    for (int kc = 0; kc < 8; ++kc) {
#pragma unroll
      for (int u = 0; u < 4; ++u) {
        int ct = h * 8 + cp * 4 + u;
        half8 b = ldg8(wvp + ((size_t)ct * 8 + kc) * 512 + lane * 8);
        acch[u] = __builtin_amdgcn_mfma_f32_16x16x32_f16(ah[kc], b, acch[u], 0, 0, 0);
        accl[u] = __builtin_amdgcn_mfma_f32_16x16x32_f16(al[kc], b, accl[u], 0, 0, 0);
      }
    }
#pragma unroll
    for (int u = 0; u < 4; ++u) {
      int ct = h * 8 + cp * 4 + u;
      int co = ct * 16 + row16;
      float bb = bv[co];
#pragma unroll
      for (int r = 0; r < 4; ++r)
        sm.exv[co][g * 16 + quad * 4 + r] = (f16)(acch[u][r] + accl[u][r] + bb);
    }
  }
  __syncthreads();
  size_t vb = ((size_t)bl * 32 + blockIdx.y) * 16;
#pragma unroll
  for (int f = 0; f < 4; ++f) {
    int ct = wave * 4 + f;
    half8 o = *reinterpret_cast<const half8*>(&sm.exv[ct * 16 + row16][quad * 8]);
    *reinterpret_cast<half8*>(vp + (vb + ct) * 512 + lane * 8) = o;
  }
}

// ---------------- fused flash attention + MLP(SiLU) + LayerNorm ----------------
// 16-WAVE 4-PARITY i-SPLIT, R7 = R6 + amdgpu_waves_per_eu(4,4).
// R6 POST-MORTEM: __launch_bounds__ second arg behaves as CUDA min-BLOCKS-per-CU on this
// toolchain: (512,2)->128 VGPR (2 blk x 8 waves = 4 w/EU), (1024,4)->64 VGPR (4 blk x 16
// waves clamped to 32 = 8 w/EU). My (1024,4) REQUESTED the 64-VGPR spill. Fix: pin the
// backend directly with amdgpu_waves_per_eu(4,4) -> exactly 4 waves/EU -> 128 VGPR/wave,
// fitting the ~127 live regs (O[16]=64, kf[8]=32, softmax ~20, addressing ~12).
struct AttnSmem {
  union {
    struct {
      f16 QB[128 * 256];   // 64 KB: packed q frags, current 128-i chunk
      f16 VB[128 * 256];   // 64 KB: packed vT frags
    } s;
    struct {
      float Ocmb[4][16][260];  // 66.6 KB: 4-way O-combine (f32)
      f16 ex[4][16][264];      // 33 KB: normalized att, then MLP hidden h (in-place)
    } e;
  } u;                      // 128 KB
  f16 P[16][16][40];        // per-wave P round-trip (C->A layout)  20.5 KB
  float ml[16][2][16];      // per-wave {m, l} per j-row             2 KB
  float lnbuf[16][2][16];   // per-wave LN partials {sum, ssq}       2 KB
};

__global__ void __launch_bounds__(1024) __attribute__((amdgpu_waves_per_eu(4, 4)))
k_attn_mlp(
    const f16* __restrict__ qp, const f16* __restrict__ kp, const f16* __restrict__ vp,
    const f16* __restrict__ w1p, const float* __restrict__ b1,
    const f16* __restrict__ w2p, const float* __restrict__ b2,
    const float* __restrict__ gamma, const float* __restrict__ beta,
    float* __restrict__ out, int b_base) {
  __shared__ AttnSmem sm;
  int bl = blockIdx.x, bg = b_base + bl;
  int j0 = blockIdx.y * 64;
  int tid = threadIdx.x, wave = tid >> 6, lane = tid & 63;
  int row16 = lane & 15, quad = lane >> 4;
  int jt_l = wave & 3, p = wave >> 2;        // j-tile within block, i-parity (0..3)
  int jw = j0 + jt_l * 16;

  // A-frags: k rows of this wave's j-tile (parity partners load the same rows; L2-hot)
  const f16* kbase = kp + (size_t)bl * NN * CC;
  int jt = (j0 >> 4) + jt_l;
  half8 kf[8];
#pragma unroll
  for (int kc = 0; kc < 8; ++kc)
    kf[kc] = ldg8(kbase + ((size_t)jt * 8 + kc) * 512 + lane * 8);

  const f16* qbase = qp + (size_t)bl * NN * CC;
  const f16* vbase = vp + (size_t)bl * CC * NN;

  // prologue: stage 128-i chunk 0 of Q and V
  stage64k16(qbase, sm.u.s.QB, wave, lane);
  stage64k16(vbase, sm.u.s.VB, wave, lane);
  VMCNT(4);   // kf(8) + Q(4) drained, V(4) in flight
  BAR();

  f32x4 O[16];
#pragma unroll
  for (int ct = 0; ct < 16; ++ct) O[ct] = {0.f, 0.f, 0.f, 0.f};
  float m_run[4], l_lane[4];
#pragma unroll
  for (int r = 0; r < 4; ++r) { m_run[r] = -1e30f; l_lane[r] = 0.f; }

  const f16* QBp = &sm.u.s.QB[p * 8192];   // parity's 32 rows = 2 16-i tiles = 16 frags
  const f16* VBp = &sm.u.s.VB[p * 8192];

  for (int it = 0; it < 8; ++it) {
    // ---- QK: scores S[16 j][32 i] from LDS, 2 parallel MFMA chains ----
    f32x4 s[2];
#pragma unroll
    for (int f = 0; f < 2; ++f) s[f] = {0.f, 0.f, 0.f, 0.f};
#pragma unroll
    for (int kc = 0; kc < 8; ++kc) {
#pragma unroll
      for (int f = 0; f < 2; ++f) {
        half8 b = *reinterpret_cast<const half8*>(&QBp[(f * 8 + kc) * 512 + lane * 8]);
        s[f] = __builtin_amdgcn_mfma_f32_16x16x32_f16(kf[kc], b, s[f], 0, 0, 0);
      }
    }
    BAR();                                                    // all waves done reading QB
    stage64k16(qbase + (size_t)((it + 1) & 7) * 32768, sm.u.s.QB, wave, lane);

    // ---- softmax per j-row over this wave's 32 i (overlaps Q staging) ----
    float alpha[4];
#pragma unroll
    for (int r = 0; r < 4; ++r) {
      float mx = fmaxf(s[0][r], s[1][r]);
#pragma unroll
      for (int off = 1; off < 16; off <<= 1) mx = fmaxf(mx, __shfl_xor(mx, off, 64));
      float mnew = fmaxf(m_run[r], mx);
      alpha[r] = __expf(m_run[r] - mnew);
      m_run[r] = mnew;
      float ps = 0.f;
#pragma unroll
      for (int f = 0; f < 2; ++f) {
        float pv = __expf(s[f][r] - mnew);
        ps += pv;
        sm.P[wave][quad * 4 + r][f * 16 + row16] = (f16)pv;
      }
      l_lane[r] = l_lane[r] * alpha[r] + ps;
    }
#pragma unroll
    for (int ct = 0; ct < 16; ++ct)
#pragma unroll
      for (int r = 0; r < 4; ++r) O[ct][r] *= alpha[r];

    VMCNT(4);    // V(it) landed (only next-Q's 4 remain in flight)
    BAR();       // all waves' V(it) visible

    // ---- PV: one 32-i chunk; P same-wave LDS round-trip, vT frags from LDS ----
    {
      half8 pf = *reinterpret_cast<const half8*>(&sm.P[wave][row16][quad * 8]);
#pragma unroll
      for (int ct = 0; ct < 16; ++ct) {
        half8 vf = *reinterpret_cast<const half8*>(&VBp[ct * 512 + lane * 8]);
        O[ct] = __builtin_amdgcn_mfma_f32_16x16x32_f16(pf, vf, O[ct], 0, 0, 0);
      }
    }
    BAR();                                                    // all waves done reading VB
    stage64k16(vbase + (size_t)((it + 1) & 7) * 32768, sm.u.s.VB, wave, lane);
    VMCNT(4);    // Q(it+1) landed (only next-V's 4 remain)
    BAR();
  }
  VMCNT(0);      // drain wrap-around stages before aliasing epilogue over QB/VB
  BAR();

  // ---- 4-way (m, l, O) combine across parity waves ----
#pragma unroll
  for (int r = 0; r < 4; ++r) {
#pragma unroll
    for (int off = 1; off < 16; off <<= 1) l_lane[r] += __shfl_xor(l_lane[r], off, 64);
  }
  if (row16 == 0) {
#pragma unroll
    for (int r = 0; r < 4; ++r) {
      sm.ml[wave][0][quad * 4 + r] = m_run[r];
      sm.ml[wave][1][quad * 4 + r] = l_lane[r];
    }
  }
  BAR();

  float aS[4], invL[4];
#pragma unroll
  for (int r = 0; r < 4; ++r) {
    int j = quad * 4 + r;
    float M = sm.ml[jt_l][0][j];
#pragma unroll
    for (int w4 = 1; w4 < 4; ++w4) M = fmaxf(M, sm.ml[jt_l + w4 * 4][0][j]);
    float L = 0.f;
#pragma unroll
    for (int w4 = 0; w4 < 4; ++w4)
      L += sm.ml[jt_l + w4 * 4][1][j] * __expf(sm.ml[jt_l + w4 * 4][0][j] - M);
    aS[r] = __expf(m_run[r] - M);
    invL[r] = 1.f / L;
  }

  // sequential rounds: p0 writes, p1/p2 add, p3 adds + normalizes into ex (f16)
  if (p == 0) {
#pragma unroll
    for (int ct = 0; ct < 16; ++ct)
#pragma unroll
      for (int r = 0; r < 4; ++r)
        sm.u.e.Ocmb[jt_l][quad * 4 + r][ct * 16 + row16] = O[ct][r] * aS[r];
  }
  BAR();
  if (p == 1) {
#pragma unroll
    for (int ct = 0; ct < 16; ++ct)
#pragma unroll
      for (int r = 0; r < 4; ++r)
        sm.u.e.Ocmb[jt_l][quad * 4 + r][ct * 16 + row16] += O[ct][r] * aS[r];
  }
  BAR();
  if (p == 2) {
#pragma unroll
    for (int ct = 0; ct < 16; ++ct)
#pragma unroll
      for (int r = 0; r < 4; ++r)
        sm.u.e.Ocmb[jt_l][quad * 4 + r][ct * 16 + row16] += O[ct][r] * aS[r];
  }
  BAR();
  if (p == 3) {
#pragma unroll
    for (int ct = 0; ct < 16; ++ct)
#pragma unroll
      for (int r = 0; r < 4; ++r) {
        float v = sm.u.e.Ocmb[jt_l][quad * 4 + r][ct * 16 + row16] + O[ct][r] * aS[r];
        sm.u.e.ex[jt_l][quad * 4 + r][ct * 16 + row16] = (f16)(v * invL[r]);
      }
  }
  BAR();   // att tile ready

  // ---- MLP + LN, 4 ct per wave ----
  half8 af[8];
#pragma unroll
  for (int kc = 0; kc < 8; ++kc)
    af[kc] = *reinterpret_cast<const half8*>(&sm.u.e.ex[jt_l][row16][kc * 32 + quad * 8]);
  BAR();   // all af reads done before h overwrites ex in place

  // GEMM1: h = silu(att @ w1 + b1) -> ex (in place, disjoint col ranges per parity)
#pragma unroll
  for (int q = 0; q < 4; ++q) {
    int ct = p * 4 + q;
    f32x4 acc = {0.f, 0.f, 0.f, 0.f};
    const f16* brow = w1p + ((size_t)ct * 8) * 512 + lane * 8;
#pragma unroll
    for (int kc = 0; kc < 8; ++kc)
      acc = __builtin_amdgcn_mfma_f32_16x16x32_f16(af[kc], ldg8(brow + kc * 512), acc, 0, 0, 0);
    int co = ct * 16 + row16;
    float bb = b1[co];
#pragma unroll
    for (int r = 0; r < 4; ++r) {
      float xg = acc[r] + bb;
      float hh = xg / (1.f + __expf(-xg));  // SiLU
      sm.u.e.ex[jt_l][quad * 4 + r][co] = (f16)hh;
    }
  }
  BAR();   // full h tile ready

  half8 hf[8];
#pragma unroll
  for (int kc = 0; kc < 8; ++kc)
    hf[kc] = *reinterpret_cast<const half8*>(&sm.u.e.ex[jt_l][row16][kc * 32 + quad * 8]);

  f32x4 acc2[4];
#pragma unroll
  for (int q = 0; q < 4; ++q) {
    int ct = p * 4 + q;
    f32x4 acc = {0.f, 0.f, 0.f, 0.f};
    const f16* brow = w2p + ((size_t)ct * 8) * 512 + lane * 8;
#pragma unroll
    for (int kc = 0; kc < 8; ++kc)
      acc = __builtin_amdgcn_mfma_f32_16x16x32_f16(hf[kc], ldg8(brow + kc * 512), acc, 0, 0, 0);
    float bb = b2[ct * 16 + row16];
#pragma unroll
    for (int r = 0; r < 4; ++r) acc[r] += bb;
    acc2[q] = acc;
  }

  // LayerNorm over C: per-wave partials (64 channels) + 4-way LDS exchange
  float sum[4] = {0.f, 0.f, 0.f, 0.f}, ssq[4] = {0.f, 0.f, 0.f, 0.f};
#pragma unroll
  for (int q = 0; q < 4; ++q)
#pragma unroll
    for (int r = 0; r < 4; ++r) { float xv = acc2[q][r]; sum[r] += xv; ssq[r] += xv * xv; }
#pragma unroll
  for (int r = 0; r < 4; ++r) {
#pragma unroll
    for (int off = 1; off < 16; off <<= 1) {
      sum[r] += __shfl_xor(sum[r], off, 64);
      ssq[r] += __shfl_xor(ssq[r], off, 64);
    }
  }
  if (row16 == 0) {
#pragma unroll
    for (int r = 0; r < 4; ++r) {
      sm.lnbuf[wave][0][quad * 4 + r] = sum[r];
      sm.lnbuf[wave][1][quad * 4 + r] = ssq[r];
    }
  }
  BAR();

  float mean[4], rstd[4];
#pragma unroll
  for (int r = 0; r < 4; ++r) {
    int j = quad * 4 + r;
    float s = 0.f, sq = 0.f;
#pragma unroll
    for (int w4 = 0; w4 < 4; ++w4) {
      s  += sm.lnbuf[jt_l + w4 * 4][0][j];
      sq += sm.lnbuf[jt_l + w4 * 4][1][j];
    }
    mean[r] = s * (1.f / 256.f);
    float var = sq * (1.f / 256.f) - mean[r] * mean[r];
    rstd[r] = rsqrtf(var + 1e-5f);
  }

  // coalesced stores: this wave's 64 channels
#pragma unroll
  for (int q = 0; q < 4; ++q) {
    int col = (p * 4 + q) * 16 + row16;
    float g = gamma[col], be = beta[col];
    f32x4 v;
#pragma unroll
    for (int r = 0; r < 4; ++r) v[r] = (acc2[q][r] - mean[r]) * rstd[r] * g + be;
    *reinterpret_cast<f32x4*>(out + (size_t)(bg * CC + col) * NN + jw + quad * 4) = v;
  }
}

extern "C" void kernel_launch(void* const* d_in, const int* in_sizes, int n_in,
                              void* d_out, int out_size, void* d_ws, size_t ws_size,
                              hipStream_t stream) {
  (void)in_sizes; (void)n_in; (void)out_size;
  const float* x     = (const float*)d_in[0];
  const float* wq    = (const float*)d_in[1];
  const float* bq    = (const float*)d_in[2];
  const float* wk    = (const float*)d_in[3];
  const float* bk    = (const float*)d_in[4];
  const float* wv    = (const float*)d_in[5];
  const float* bv    = (const float*)d_in[6];
  const float* w1    = (const float*)d_in[7];
  const float* b1    = (const float*)d_in[8];
  const float* w2    = (const float*)d_in[9];
  const float* b2    = (const float*)d_in[10];
  const float* gamma = (const float*)d_in[11];
  const float* beta  = (const float*)d_in[12];
  float* out = (float*)d_out;

  const size_t WE = 65536;
  const size_t SB = (size_t)NN * CC;
  f16* base = (f16*)d_ws;
  f16* wqp = base + 0 * WE;
  f16* wkp = base + 1 * WE;
  f16* wvp = base + 2 * WE;
  f16* w1p = base + 3 * WE;
  f16* w2p = base + 4 * WE;

  size_t wbytes = 5 * WE * sizeof(f16);
  size_t perb   = 3 * SB * sizeof(f16);
  int nb = (ws_size > wbytes) ? (int)((ws_size - wbytes) / perb) : 1;
  if (nb < 1) nb = 1;
  if (nb > BB) nb = BB;

  f16* qb  = base + 5 * WE;
  f16* kb  = qb + (size_t)nb * SB;
  f16* vTb = kb + (size_t)nb * SB;

  WP5 p;
  p.s[0] = wq; p.s[1] = wk; p.s[2] = wv; p.s[3] = w1; p.s[4] = w2;
  p.d[0] = wqp; p.d[1] = wkp; p.d[2] = wvp; p.d[3] = w1p; p.d[4] = w2p;
  k_packW<<<dim3(16, 5), 256, 0, stream>>>(p);

  for (int b0 = 0; b0 < BB; b0 += nb) {
    int cb = (b0 + nb <= BB) ? nb : (BB - b0);
    k_qkv<<<dim3(cb, 32), 256, 0, stream>>>(x, wqp, wkp, wvp, bq, bk, bv, qb, kb, vTb, b0);
    k_attn_mlp<<<dim3(cb, 16), 1024, 0, stream>>>(qb, kb, vTb, w1p, b1, w2p, b2,
                                                  gamma, beta, out, b0);
  }
}

// Round 8
// 187.500 us; speedup vs baseline: 1.1232x; 1.1232x over previous
//
#include <hip/hip_runtime.h>

#define BB 16
#define CC 256
#define NN 1024

typedef _Float16 f16;
typedef __attribute__((ext_vector_type(8))) _Float16 half8;   // MFMA A/B frag (4 VGPRs)
typedef __attribute__((ext_vector_type(4))) float f32x4;      // MFMA C/D frag

__device__ __forceinline__ half8 ldg8(const f16* p) {
  return *reinterpret_cast<const half8*>(p);
}

// async global->LDS, 16B per lane; lds base must be wave-uniform (HW adds lane*16)
__device__ __forceinline__ void gll16(const f16* g, f16* l) {
  __builtin_amdgcn_global_load_lds((const __attribute__((address_space(1))) void*)g,
                                   (__attribute__((address_space(3))) void*)l, 16, 0, 0);
}

#define VMCNT(n) asm volatile("s_waitcnt vmcnt(" #n ")" ::: "memory")
#define BAR() __builtin_amdgcn_s_barrier()

// stage one contiguous 32 KB chunk (16384 f16) with 512 threads (8 waves): 4 issues/thread.
__device__ __forceinline__ void stage32k8(const f16* __restrict__ g, f16* l, int wave, int lane) {
#pragma unroll
  for (int k = 0; k < 4; ++k) {
    int ob = k * 4096 + wave * 512;      // 8 waves x 512 = 4096 per k
    gll16(g + ob + lane * 8, l + ob);
  }
}

// ---------------- weight pack: W fp32 [ci][co] -> frag-packed f16 wp[(ct*8+kc)*512 + lane*8] ----
struct WP5 {
  const float* s[5];
  f16* d[5];
};

__global__ void __launch_bounds__(256) k_packW(WP5 p) {
  __shared__ float ws[256][17];
  int m = blockIdx.y, ct = blockIdx.x;
  const float* W = p.s[m];
  f16* wp = p.d[m];
  int tid = threadIdx.x;
  int col = tid & 15, cig = tid >> 4;
#pragma unroll
  for (int pg = 0; pg < 16; ++pg) {
    int ci = pg * 16 + cig;
    ws[ci][col] = W[(size_t)ci * 256 + ct * 16 + col];
  }
  __syncthreads();
  int lane = tid & 63, wave = tid >> 6;
  int row16 = lane & 15, quad = lane >> 4;
#pragma unroll
  for (int kk = 0; kk < 2; ++kk) {
    int kc = wave * 2 + kk;
    half8 o;
#pragma unroll
    for (int j = 0; j < 8; ++j) o[j] = (f16)ws[kc * 32 + quad * 8 + j][row16];
    *reinterpret_cast<half8*>(wp + ((size_t)ct * 8 + kc) * 512 + lane * 8) = o;
  }
}

// ---------------- QKV (z-merged, unchanged from R3/R4) ----------------
struct QkvSmem {
  union {
    struct { f16 hi[32][264]; f16 lo[32][264]; } ts;
    f16 ex[2][16][264];
    f16 exv[256][40];
  };
};

__global__ void __launch_bounds__(256) k_qkv(const float* __restrict__ x,
    const f16* __restrict__ wqp, const f16* __restrict__ wkp, const f16* __restrict__ wvp,
    const float* __restrict__ bq, const float* __restrict__ bk, const float* __restrict__ bv,
    f16* __restrict__ qp, f16* __restrict__ kp, f16* __restrict__ vp, int b_base) {
  __shared__ QkvSmem sm;
  int bl = blockIdx.x, bg = b_base + bl, n0 = blockIdx.y * 32;
  int tid = threadIdx.x, wave = tid >> 6, lane = tid & 63;
  int row16 = lane & 15, quad = lane >> 4;
  int g = wave >> 1, h = wave & 1;

#pragma unroll
  for (int e = tid; e < 2048; e += 256) {
    int c = e >> 3, n4 = (e & 7) << 2;
    float4 u = *reinterpret_cast<const float4*>(x + (size_t)(bg * CC + c) * NN + n0 + n4);
    float uv[4] = {u.x, u.y, u.z, u.w};
#pragma unroll
    for (int i = 0; i < 4; ++i) {
      f16 hh = (f16)uv[i];
      sm.ts.hi[n4 + i][c] = hh;
      sm.ts.lo[n4 + i][c] = (f16)(uv[i] - (float)hh);
    }
  }
  __syncthreads();

  half8 ah[8], al[8];
#pragma unroll
  for (int kc = 0; kc < 8; ++kc) {
    ah[kc] = *reinterpret_cast<const half8*>(&sm.ts.hi[g * 16 + row16][kc * 32 + quad * 8]);
    al[kc] = *reinterpret_cast<const half8*>(&sm.ts.lo[g * 16 + row16][kc * 32 + quad * 8]);
  }
  __syncthreads();

  const f16* WTs[2]    = {wqp, wkp};
  const float* biases[2] = {bq, bk};
  f16* outs[2]         = {qp, kp};
#pragma unroll
  for (int z = 0; z < 2; ++z) {
    const f16* WT = WTs[z];
    const float* bias = biases[z];
    f16* outp = outs[z];
#pragma unroll
    for (int cp = 0; cp < 2; ++cp) {
      f32x4 acch[4], accl[4];
#pragma unroll
      for (int u = 0; u < 4; ++u) { acch[u] = {0.f,0.f,0.f,0.f}; accl[u] = {0.f,0.f,0.f,0.f}; }
#pragma unroll
      for (int kc = 0; kc < 8; ++kc) {
#pragma unroll
        for (int u = 0; u < 4; ++u) {
          int ct = h * 8 + cp * 4 + u;
          half8 b = ldg8(WT + ((size_t)ct * 8 + kc) * 512 + lane * 8);
          acch[u] = __builtin_amdgcn_mfma_f32_16x16x32_f16(ah[kc], b, acch[u], 0, 0, 0);
          accl[u] = __builtin_amdgcn_mfma_f32_16x16x32_f16(al[kc], b, accl[u], 0, 0, 0);
        }
      }
#pragma unroll
      for (int u = 0; u < 4; ++u) {
        int ct = h * 8 + cp * 4 + u;
        int co = ct * 16 + row16;
        float bb = bias[co];
#pragma unroll
        for (int r = 0; r < 4; ++r)
          sm.ex[g][quad * 4 + r][co] = (f16)(acch[u][r] + accl[u][r] + bb);
      }
    }
    const f16* exr = &sm.ex[g][row16][0];
    size_t fb = ((size_t)bl * 64 + (n0 >> 4) + g) * 8;
#pragma unroll
    for (int k = 0; k < 4; ++k) {
      int kc = h * 4 + k;
      half8 hv = *reinterpret_cast<const half8*>(exr + kc * 32 + quad * 8);
      *reinterpret_cast<half8*>(outp + (fb + kc) * 512 + lane * 8) = hv;
    }
  }
  __syncthreads();

#pragma unroll
  for (int cp = 0; cp < 2; ++cp) {
    f32x4 acch[4], accl[4];
#pragma unroll
    for (int u = 0; u < 4; ++u) { acch[u] = {0.f,0.f,0.f,0.f}; accl[u] = {0.f,0.f,0.f,0.f}; }
#pragma unroll
    for (int kc = 0; kc < 8; ++kc) {
#pragma unroll
      for (int u = 0; u < 4; ++u) {
        int ct = h * 8 + cp * 4 + u;
        half8 b = ldg8(wvp + ((size_t)ct * 8 + kc) * 512 + lane * 8);
        acch[u] = __builtin_amdgcn_mfma_f32_16x16x32_f16(ah[kc], b, acch[u], 0, 0, 0);
        accl[u] = __builtin_amdgcn_mfma_f32_16x16x32_f16(al[kc], b, accl[u], 0, 0, 0);
      }
    }
#pragma unroll
    for (int u = 0; u < 4; ++u) {
      int ct = h * 8 + cp * 4 + u;
      int co = ct * 16 + row16;
      float bb = bv[co];
#pragma unroll
      for (int r = 0; r < 4; ++r)
        sm.exv[co][g * 16 + quad * 4 + r] = (f16)(acch[u][r] + accl[u][r] + bb);
    }
  }
  __syncthreads();
  size_t vb = ((size_t)bl * 32 + blockIdx.y) * 16;
#pragma unroll
  for (int f = 0; f < 4; ++f) {
    int ct = wave * 4 + f;
    half8 o = *reinterpret_cast<const half8*>(&sm.exv[ct * 16 + row16][quad * 8]);
    *reinterpret_cast<half8*>(vp + (vb + ct) * 512 + lane * 8) = o;
  }
}

// ---------------- fused flash attention + MLP(SiLU) + LayerNorm ----------------
// R8: 8-WAVE (512-thread) BLOCK, 2 BLOCKS/CU. R5-R7 post-mortem: 1024-thread blocks get
// VGPR=64 from the allocator no matter the declaration ((1024,4) and waves_per_eu both
// ignored/counter-productive); only (512,2) provably yields 128 VGPR (R4). So reach
// 4 waves/SIMD via 2 x 8-wave blocks: LDS cut to ~78 KB by staging 64-i chunks
// (32 KB Q + 32 KB V) over 16 iterations. Same traffic, same per-wave work/iter (32 i).
// Bonus vs monolithic 16-wave: the two resident blocks are INDEPENDENT — one block's
// barrier/vmcnt stall is covered by the other's waves.
// Epilogue: 2-way parity combine in two ct-half rounds through a 33 KB f32 buffer;
// MLP hidden h aliases the dead combine buffer.
struct AttnSmem {
  union {
    struct {
      f16 QB[64 * 256];        // 32 KB: packed q frags, current 64-i chunk
      f16 VB[64 * 256];        // 32 KB: packed vT frags
    } s;
    struct {
      float Ocmb[4][16][132];  // 33 KB: ct-half combine buffer (later aliased as h ex2)
      f16 ex[4][16][264];      // 33 KB: normalized att (persists across both rounds)
    } e;
  } u;                      // 67584 B
  f16 P[8][16][40];         // per-wave P round-trip (C->A layout)  10240 B
  float ml[8][2][16];       // per-wave {m, l} per j-row             1024 B
  float lnbuf[8][2][16];    // per-wave LN partials {sum, ssq}       1024 B
};                          // total 79872 B <= 80 KB -> 2 blocks/CU

__global__ void __launch_bounds__(512, 2) k_attn_mlp(
    const f16* __restrict__ qp, const f16* __restrict__ kp, const f16* __restrict__ vp,
    const f16* __restrict__ w1p, const float* __restrict__ b1,
    const f16* __restrict__ w2p, const float* __restrict__ b2,
    const float* __restrict__ gamma, const float* __restrict__ beta,
    float* __restrict__ out, int b_base) {
  __shared__ AttnSmem sm;
  int bl = blockIdx.x, bg = b_base + bl;
  int j0 = blockIdx.y * 64;
  int tid = threadIdx.x, wave = tid >> 6, lane = tid & 63;
  int row16 = lane & 15, quad = lane >> 4;
  int jt_l = wave & 3, p = wave >> 2;        // j-tile within block, i-parity (0..1)
  int jw = j0 + jt_l * 16;

  // A-frags: k rows of this wave's j-tile (parity partner loads the same rows; L2-hot)
  const f16* kbase = kp + (size_t)bl * NN * CC;
  int jt = (j0 >> 4) + jt_l;
  half8 kf[8];
#pragma unroll
  for (int kc = 0; kc < 8; ++kc)
    kf[kc] = ldg8(kbase + ((size_t)jt * 8 + kc) * 512 + lane * 8);

  const f16* qbase = qp + (size_t)bl * NN * CC;
  const f16* vbase = vp + (size_t)bl * CC * NN;

  // prologue: stage 64-i chunk 0 of Q and V
  stage32k8(qbase, sm.u.s.QB, wave, lane);
  stage32k8(vbase, sm.u.s.VB, wave, lane);
  VMCNT(4);   // kf(8) + Q(4) drained, V(4) in flight
  BAR();

  f32x4 O[16];
#pragma unroll
  for (int ct = 0; ct < 16; ++ct) O[ct] = {0.f, 0.f, 0.f, 0.f};
  float m_run[4], l_lane[4];
#pragma unroll
  for (int r = 0; r < 4; ++r) { m_run[r] = -1e30f; l_lane[r] = 0.f; }

  const f16* QBp = &sm.u.s.QB[p * 8192];   // parity's 32 rows = 2 16-i tiles = 16 frags
  const f16* VBp = &sm.u.s.VB[p * 8192];

  for (int it = 0; it < 16; ++it) {
    // ---- QK: scores S[16 j][32 i] from LDS, 2 parallel MFMA chains ----
    f32x4 s[2];
#pragma unroll
    for (int f = 0; f < 2; ++f) s[f] = {0.f, 0.f, 0.f, 0.f};
#pragma unroll
    for (int kc = 0; kc < 8; ++kc) {
#pragma unroll
      for (int f = 0; f < 2; ++f) {
        half8 b = *reinterpret_cast<const half8*>(&QBp[(f * 8 + kc) * 512 + lane * 8]);
        s[f] = __builtin_amdgcn_mfma_f32_16x16x32_f16(kf[kc], b, s[f], 0, 0, 0);
      }
    }
    BAR();                                                    // all waves done reading QB
    stage32k8(qbase + (size_t)((it + 1) & 15) * 16384, sm.u.s.QB, wave, lane);

    // ---- softmax per j-row over this wave's 32 i (overlaps Q staging) ----
    float alpha[4];
#pragma unroll
    for (int r = 0; r < 4; ++r) {
      float mx = fmaxf(s[0][r], s[1][r]);
#pragma unroll
      for (int off = 1; off < 16; off <<= 1) mx = fmaxf(mx, __shfl_xor(mx, off, 64));
      float mnew = fmaxf(m_run[r], mx);
      alpha[r] = __expf(m_run[r] - mnew);
      m_run[r] = mnew;
      float ps = 0.f;
#pragma unroll
      for (int f = 0; f < 2; ++f) {
        float pv = __expf(s[f][r] - mnew);
        ps += pv;
        sm.P[wave][quad * 4 + r][f * 16 + row16] = (f16)pv;
      }
      l_lane[r] = l_lane[r] * alpha[r] + ps;
    }
#pragma unroll
    for (int ct = 0; ct < 16; ++ct)
#pragma unroll
      for (int r = 0; r < 4; ++r) O[ct][r] *= alpha[r];

    VMCNT(4);    // V(it) landed (only next-Q's 4 remain in flight)
    BAR();       // all waves' V(it) visible

    // ---- PV: one 32-i chunk; P same-wave LDS round-trip, vT frags from LDS ----
    {
      half8 pf = *reinterpret_cast<const half8*>(&sm.P[wave][row16][quad * 8]);
#pragma unroll
      for (int ct = 0; ct < 16; ++ct) {
        half8 vf = *reinterpret_cast<const half8*>(&VBp[ct * 512 + lane * 8]);
        O[ct] = __builtin_amdgcn_mfma_f32_16x16x32_f16(pf, vf, O[ct], 0, 0, 0);
      }
    }
    BAR();                                                    // all waves done reading VB
    stage32k8(vbase + (size_t)((it + 1) & 15) * 16384, sm.u.s.VB, wave, lane);
    VMCNT(4);    // Q(it+1) landed (only next-V's 4 remain)
    BAR();
  }
  VMCNT(0);      // drain wrap-around stages before aliasing epilogue over QB/VB
  BAR();

  // ---- pairwise (m, l, O) combine across parity waves, in two ct-half rounds ----
#pragma unroll
  for (int r = 0; r < 4; ++r) {
#pragma unroll
    for (int off = 1; off < 16; off <<= 1) l_lane[r] += __shfl_xor(l_lane[r], off, 64);
  }
  if (row16 == 0) {
#pragma unroll
    for (int r = 0; r < 4; ++r) {
      sm.ml[wave][0][quad * 4 + r] = m_run[r];
      sm.ml[wave][1][quad * 4 + r] = l_lane[r];
    }
  }
  BAR();

  int partner = wave ^ 4;
  float aS[4], invL[4];
#pragma unroll
  for (int r = 0; r < 4; ++r) {
    int j = quad * 4 + r;
    float ma = m_run[r], mb = sm.ml[partner][0][j];
    float M = fmaxf(ma, mb);
    float L = l_lane[r] * __expf(ma - M) + sm.ml[partner][1][j] * __expf(mb - M);
    aS[r] = __expf(ma - M);
    invL[r] = 1.f / L;
  }
#pragma unroll
  for (int ct = 0; ct < 16; ++ct)
#pragma unroll
    for (int r = 0; r < 4; ++r) O[ct][r] *= aS[r];

  // round A: ct 0..7 (cols 0..127)
  if (p == 0) {
#pragma unroll
    for (int ct = 0; ct < 8; ++ct)
#pragma unroll
      for (int r = 0; r < 4; ++r)
        sm.u.e.Ocmb[jt_l][quad * 4 + r][ct * 16 + row16] = O[ct][r];
  }
  BAR();
  if (p == 1) {
#pragma unroll
    for (int ct = 0; ct < 8; ++ct)
#pragma unroll
      for (int r = 0; r < 4; ++r) {
        float v = sm.u.e.Ocmb[jt_l][quad * 4 + r][ct * 16 + row16] + O[ct][r];
        sm.u.e.ex[jt_l][quad * 4 + r][ct * 16 + row16] = (f16)(v * invL[r]);
      }
  }
  BAR();
  // round B: ct 8..15 (cols 128..255)
  if (p == 0) {
#pragma unroll
    for (int ct = 8; ct < 16; ++ct)
#pragma unroll
      for (int r = 0; r < 4; ++r)
        sm.u.e.Ocmb[jt_l][quad * 4 + r][(ct - 8) * 16 + row16] = O[ct][r];
  }
  BAR();
  if (p == 1) {
#pragma unroll
    for (int ct = 8; ct < 16; ++ct)
#pragma unroll
      for (int r = 0; r < 4; ++r) {
        float v = sm.u.e.Ocmb[jt_l][quad * 4 + r][(ct - 8) * 16 + row16] + O[ct][r];
        sm.u.e.ex[jt_l][quad * 4 + r][ct * 16 + row16] = (f16)(v * invL[r]);
      }
  }
  BAR();   // att tile ready; Ocmb dead -> reusable as h (ex2)

  // ---- MLP + LN, 8 ct per wave (ct-halves split across the parity pair) ----
  half8 af[8];
#pragma unroll
  for (int kc = 0; kc < 8; ++kc)
    af[kc] = *reinterpret_cast<const half8*>(&sm.u.e.ex[jt_l][row16][kc * 32 + quad * 8]);

  f16* ex2 = reinterpret_cast<f16*>(&sm.u.e.Ocmb[0][0][0]);   // [4][16][264] f16, 33 KB

  // GEMM1: h = silu(att @ w1 + b1) -> ex2 (this wave's 8 ct)
#pragma unroll
  for (int q8 = 0; q8 < 8; ++q8) {
    int ct = p * 8 + q8;
    f32x4 acc = {0.f, 0.f, 0.f, 0.f};
    const f16* brow = w1p + ((size_t)ct * 8) * 512 + lane * 8;
#pragma unroll
    for (int kc = 0; kc < 8; ++kc)
      acc = __builtin_amdgcn_mfma_f32_16x16x32_f16(af[kc], ldg8(brow + kc * 512), acc, 0, 0, 0);
    int co = ct * 16 + row16;
    float bb = b1[co];
#pragma unroll
    for (int r = 0; r < 4; ++r) {
      float xg = acc[r] + bb;
      float hh = xg / (1.f + __expf(-xg));  // SiLU
      ex2[((size_t)jt_l * 16 + quad * 4 + r) * 264 + co] = (f16)hh;
    }
  }
  BAR();   // full h tile ready

  half8 hf[8];
#pragma unroll
  for (int kc = 0; kc < 8; ++kc)
    hf[kc] = *reinterpret_cast<const half8*>(&ex2[((size_t)jt_l * 16 + row16) * 264 + kc * 32 + quad * 8]);

  f32x4 acc2[8];
#pragma unroll
  for (int q8 = 0; q8 < 8; ++q8) {
    int ct = p * 8 + q8;
    f32x4 acc = {0.f, 0.f, 0.f, 0.f};
    const f16* brow = w2p + ((size_t)ct * 8) * 512 + lane * 8;
#pragma unroll
    for (int kc = 0; kc < 8; ++kc)
      acc = __builtin_amdgcn_mfma_f32_16x16x32_f16(hf[kc], ldg8(brow + kc * 512), acc, 0, 0, 0);
    float bb = b2[ct * 16 + row16];
#pragma unroll
    for (int r = 0; r < 4; ++r) acc[r] += bb;
    acc2[q8] = acc;
  }

  // LayerNorm over C: per-wave partials (128 channels) + pairwise LDS exchange
  float sum[4] = {0.f, 0.f, 0.f, 0.f}, ssq[4] = {0.f, 0.f, 0.f, 0.f};
#pragma unroll
  for (int q8 = 0; q8 < 8; ++q8)
#pragma unroll
    for (int r = 0; r < 4; ++r) { float xv = acc2[q8][r]; sum[r] += xv; ssq[r] += xv * xv; }
#pragma unroll
  for (int r = 0; r < 4; ++r) {
#pragma unroll
    for (int off = 1; off < 16; off <<= 1) {
      sum[r] += __shfl_xor(sum[r], off, 64);
      ssq[r] += __shfl_xor(ssq[r], off, 64);
    }
  }
  if (row16 == 0) {
#pragma unroll
    for (int r = 0; r < 4; ++r) {
      sm.lnbuf[wave][0][quad * 4 + r] = sum[r];
      sm.lnbuf[wave][1][quad * 4 + r] = ssq[r];
    }
  }
  BAR();

  float mean[4], rstd[4];
#pragma unroll
  for (int r = 0; r < 4; ++r) {
    int j = quad * 4 + r;
    float s  = sm.lnbuf[wave][0][j] + sm.lnbuf[partner][0][j];
    float sq = sm.lnbuf[wave][1][j] + sm.lnbuf[partner][1][j];
    mean[r] = s * (1.f / 256.f);
    float var = sq * (1.f / 256.f) - mean[r] * mean[r];
    rstd[r] = rsqrtf(var + 1e-5f);
  }

  // coalesced stores: this wave's 128 channels
#pragma unroll
  for (int q8 = 0; q8 < 8; ++q8) {
    int col = (p * 8 + q8) * 16 + row16;
    float g = gamma[col], be = beta[col];
    f32x4 v;
#pragma unroll
    for (int r = 0; r < 4; ++r) v[r] = (acc2[q8][r] - mean[r]) * rstd[r] * g + be;
    *reinterpret_cast<f32x4*>(out + (size_t)(bg * CC + col) * NN + jw + quad * 4) = v;
  }
}

extern "C" void kernel_launch(void* const* d_in, const int* in_sizes, int n_in,
                              void* d_out, int out_size, void* d_ws, size_t ws_size,
                              hipStream_t stream) {
  (void)in_sizes; (void)n_in; (void)out_size;
  const float* x     = (const float*)d_in[0];
  const float* wq    = (const float*)d_in[1];
  const float* bq    = (const float*)d_in[2];
  const float* wk    = (const float*)d_in[3];
  const float* bk    = (const float*)d_in[4];
  const float* wv    = (const float*)d_in[5];
  const float* bv    = (const float*)d_in[6];
  const float* w1    = (const float*)d_in[7];
  const float* b1    = (const float*)d_in[8];
  const float* w2    = (const float*)d_in[9];
  const float* b2    = (const float*)d_in[10];
  const float* gamma = (const float*)d_in[11];
  const float* beta  = (const float*)d_in[12];
  float* out = (float*)d_out;

  const size_t WE = 65536;
  const size_t SB = (size_t)NN * CC;
  f16* base = (f16*)d_ws;
  f16* wqp = base + 0 * WE;
  f16* wkp = base + 1 * WE;
  f16* wvp = base + 2 * WE;
  f16* w1p = base + 3 * WE;
  f16* w2p = base + 4 * WE;

  size_t wbytes = 5 * WE * sizeof(f16);
  size_t perb   = 3 * SB * sizeof(f16);
  int nb = (ws_size > wbytes) ? (int)((ws_size - wbytes) / perb) : 1;
  if (nb < 1) nb = 1;
  if (nb > BB) nb = BB;

  f16* qb  = base + 5 * WE;
  f16* kb  = qb + (size_t)nb * SB;
  f16* vTb = kb + (size_t)nb * SB;

  WP5 p;
  p.s[0] = wq; p.s[1] = wk; p.s[2] = wv; p.s[3] = w1; p.s[4] = w2;
  p.d[0] = wqp; p.d[1] = wkp; p.d[2] = wvp; p.d[3] = w1p; p.d[4] = w2p;
  k_packW<<<dim3(16, 5), 256, 0, stream>>>(p);

  for (int b0 = 0; b0 < BB; b0 += nb) {
    int cb = (b0 + nb <= BB) ? nb : (BB - b0);
    k_qkv<<<dim3(cb, 32), 256, 0, stream>>>(x, wqp, wkp, wvp, bq, bk, bv, qb, kb, vTb, b0);
    k_attn_mlp<<<dim3(cb, 16), 512, 0, stream>>>(qb, kb, vTb, w1p, b1, w2p, b2,
                                                 gamma, beta, out, b0);
  }
}